// Round 7
// baseline (56.803 us; speedup 1.0000x reference)
//
#include <hip/hip_runtime.h>

#define NEG_SLOPE 0.2f

typedef __bf16 bf16x8 __attribute__((ext_vector_type(8)));
typedef float  f32x4  __attribute__((ext_vector_type(4)));

__device__ __forceinline__ float leaky(float v)  { return v > 0.f ? v : NEG_SLOPE * v; }
__device__ __forceinline__ float relu_f(float v) { return v > 0.f ? v : 0.f; }

// ---------------- prep: W1/W2 -> bf16 MFMA B-fragment order in d_ws ----------------
// W1F[(n*64 + l)*8 + j] = bf16(W1[(l4*8+j)*128 + n*16+l15]),  n=0..7
// W2F[((ks*2+nn)*64 + l)*8 + j] = bf16(W2[(ks*32+l4*8+j)*32 + nn*16+l15])
// -> in the main kernel a wave's B-frag load is 64 consecutive bf16x8 = 1 KB contiguous.
__global__ __launch_bounds__(256)
void prep_weights(const float* __restrict__ W1, const float* __restrict__ W2,
                  __bf16* __restrict__ W1F, __bf16* __restrict__ W2F)
{
    int idx = blockIdx.x * 256 + threadIdx.x;   // 0..8191
    int half = idx >> 12;                        // 0: W1, 1: W2
    int e    = idx & 4095;
    int j   = e & 7;
    int l   = (e >> 3) & 63;
    int t   = e >> 9;                            // 0..7
    int l15 = l & 15;
    int l4  = l >> 4;
    if (half == 0) {
        W1F[e] = (__bf16)W1[(l4 * 8 + j) * 128 + t * 16 + l15];
    } else {
        int ks = t >> 1, nn = t & 1;
        W2F[e] = (__bf16)W2[(ks * 32 + l4 * 8 + j) * 32 + nn * 16 + l15];
    }
}

// Block = 256 threads = 4 waves, 64 samples/block.
// GAT phase : wave w -> g = w&1 (graph), ch = (w>>1)&1 (channel half, 8 ch);
//             lane = sample-in-block. Weight indices uniform -> s_load.
//             NO occupancy attributes (R2-R4: every hint => 64-reg spill).
// MLP phase : MFMA 16x16x32 bf16, B-frags pre-laid-out in d_ws (coalesced, L2-hot).
__global__ __launch_bounds__(256)
void scl_fused_kernel(
    const float* __restrict__ agent_pos, const float* __restrict__ agent_vel,
    const float* __restrict__ rel_lm, const float* __restrict__ other_pos,
    const float* __restrict__ lm_pos,
    const float* __restrict__ Wl, const float* __restrict__ bl,
    const float* __restrict__ Wr, const float* __restrict__ br,
    const float* __restrict__ We, const float* __restrict__ att,
    const float* __restrict__ bias,
    const float* __restrict__ b1, const float* __restrict__ b2,
    const bf16x8* __restrict__ W1F, const bf16x8* __restrict__ W2F,
    float* __restrict__ out, int Btot)
{
    __shared__ float lds_lp[2][2][64][9];              // [g][ch][sample][edge] logit partials
    __shared__ alignas(16) __bf16 lds_h[64][40];       // pooled GAT out, stride 40 bf16
    __shared__ alignas(16) __bf16 lds_z[4][16][136];   // per-wave z, stride 136 bf16

    const int tid  = threadIdx.x;
    const int lane = tid & 63;                         // sample-in-block == lane-in-wave
    const int w    = tid >> 6;
    const int g    = __builtin_amdgcn_readfirstlane(w & 1);
    const int ch   = __builtin_amdgcn_readfirstlane((w >> 1) & 1);
    const int wu   = __builtin_amdgcn_readfirstlane(w);
    const int CB   = ch * 8;                           // channel base (uniform)

    int b = blockIdx.x * 64 + lane;
    if (b >= Btot) b = Btot - 1;                       // clamp reads; barriers stay uniform

    const int o0[3] = {1, 0, 0};
    const int o1[3] = {2, 2, 1};

    // ---- positions (uniform branch) ----
    float px[3], py[3];
    if (g == 0) {
        const float2* ap = reinterpret_cast<const float2*>(agent_pos + b * 6);
#pragma unroll
        for (int j = 0; j < 3; ++j) { px[j] = ap[j].x; py[j] = ap[j].y; }
    } else {
        const float2* lp2 = reinterpret_cast<const float2*>(lm_pos + b * 18);
#pragma unroll
        for (int m = 0; m < 3; ++m) { px[m] = lp2[m].x; py[m] = lp2[m].y; }
    }

    // ---- pairwise distances ----
    float d01, d02, d12;
    {
        float dx, dy, sq;
        dx = px[0] - px[1]; dy = py[0] - py[1]; sq = dx * dx + dy * dy;
        d01 = sq > 0.f ? sqrtf(sq) : 0.f;
        dx = px[0] - px[2]; dy = py[0] - py[2]; sq = dx * dx + dy * dy;
        d02 = sq > 0.f ? sqrtf(sq) : 0.f;
        dx = px[1] - px[2]; dy = py[1] - py[2]; sq = dx * dx + dy * dy;
        d12 = sq > 0.f ? sqrtf(sq) : 0.f;
    }

    // ---- xl/xr for my 8 channels (weights scalar: CB uniform) ----
    float xl[3][8], xr[3][8];
#pragma unroll
    for (int j = 0; j < 3; ++j) {
        float xf[14];
        if (g == 0) {
            const float2 vel = reinterpret_cast<const float2*>(agent_vel + b * 6)[j];
            const float2* rl = reinterpret_cast<const float2*>(rel_lm + b * 18 + j * 6);
            const float4 op  = reinterpret_cast<const float4*>(other_pos + b * 12)[j];
            xf[0] = px[j]; xf[1] = py[j];
            xf[2] = vel.x; xf[3] = vel.y;
            xf[4] = rl[0].x; xf[5] = rl[0].y;
            xf[6] = rl[1].x; xf[7] = rl[1].y;
            xf[8] = rl[2].x; xf[9] = rl[2].y;
            xf[10] = op.x; xf[11] = op.y; xf[12] = op.z; xf[13] = op.w;
        } else {
            xf[0] = px[j]; xf[1] = py[j];
            xf[2] = 0.f;   xf[3] = 0.f;
#pragma unroll
            for (int m = 0; m < 3; ++m) {
                xf[4 + 2 * m] = px[m] - px[j];
                xf[5 + 2 * m] = py[m] - py[j];
            }
            const int a = o0[j], c2 = o1[j];
            xf[10] = px[a]  - px[j]; xf[11] = py[a]  - py[j];
            xf[12] = px[c2] - px[j]; xf[13] = py[c2] - py[j];
        }
#pragma unroll
        for (int cc = 0; cc < 8; ++cc) { xl[j][cc] = bl[CB + cc]; xr[j][cc] = br[CB + cc]; }
#pragma unroll
        for (int k = 0; k < 14; ++k) {
#pragma unroll
            for (int cc = 0; cc < 8; ++cc) {
                xl[j][cc] = fmaf(xf[k], Wl[k * 16 + CB + cc], xl[j][cc]);
                xr[j][cc] = fmaf(xf[k], Wr[k * 16 + CB + cc], xr[j][cc]);
            }
        }
    }

    // ---- logit partials over my 8 channels, all 9 edges ----
    float lp[9];
#pragma unroll
    for (int i = 0; i < 3; ++i) {
#pragma unroll
        for (int j = 0; j < 3; ++j) {
            float axv, ayv, adv;
            if (i == j) {
                const int a = o0[i], c2 = o1[i];
                axv = 0.5f * (px[a] + px[c2]) - px[i];
                ayv = 0.5f * (py[a] + py[c2]) - py[i];
                const float dA = (i == 0) ? d01 : ((i == 1) ? d01 : d02);
                const float dB = (i == 0) ? d02 : ((i == 1) ? d12 : d12);
                adv = 0.5f * (dA + dB);
            } else {
                axv = px[j] - px[i];
                ayv = py[j] - py[i];
                adv = ((i == 0 && j == 1) || (i == 1 && j == 0)) ? d01
                    : ((i == 0 && j == 2) || (i == 2 && j == 0)) ? d02 : d12;
            }
            float acc = 0.f;
#pragma unroll
            for (int cc = 0; cc < 8; ++cc) {
                float gg = xl[j][cc] + xr[i][cc];
                gg = fmaf(axv, We[CB + cc], gg);
                gg = fmaf(ayv, We[16 + CB + cc], gg);
                gg = fmaf(adv, We[32 + CB + cc], gg);
                acc = fmaf(leaky(gg), att[CB + cc], acc);
            }
            lp[j * 3 + i] = acc;
        }
    }

    // ---- exchange partials with sibling channel-half ----
#pragma unroll
    for (int e = 0; e < 9; ++e) lds_lp[g][ch][lane][e] = lp[e];
    __syncthreads();    // B1

    float lg[9];
#pragma unroll
    for (int e = 0; e < 9; ++e) lg[e] = lp[e] + lds_lp[g][1 - ch][lane][e];

    // ---- softmax per target + pooled relu-sum over my 8 channels ----
    float hs[8] = {0.f, 0.f, 0.f, 0.f, 0.f, 0.f, 0.f, 0.f};
#pragma unroll
    for (int i = 0; i < 3; ++i) {
        float m = fmaxf(lg[i], fmaxf(lg[3 + i], lg[6 + i]));
        float e0 = __expf(lg[i] - m);
        float e1 = __expf(lg[3 + i] - m);
        float e2 = __expf(lg[6 + i] - m);
        float inv = __builtin_amdgcn_rcpf(e0 + e1 + e2);
        float a0 = e0 * inv, a1 = e1 * inv, a2 = e2 * inv;
#pragma unroll
        for (int cc = 0; cc < 8; ++cc) {
            float v = fmaf(a0, xl[0][cc],
                      fmaf(a1, xl[1][cc],
                      fmaf(a2, xl[2][cc], bias[CB + cc])));
            hs[cc] += relu_f(v);
        }
    }

    // ---- publish pooled h as bf16 ----
    {
        bf16x8 hv;
#pragma unroll
        for (int cc = 0; cc < 8; ++cc) hv[cc] = (__bf16)hs[cc];
        *reinterpret_cast<bf16x8*>(&lds_h[lane][g * 16 + CB]) = hv;   // 16B-aligned
    }
    __syncthreads();    // B2

    // ================= MLP via MFMA 16x16x32 bf16 =================
    const int l15 = lane & 15;
    const int l4  = lane >> 4;
    const int Mrow0 = wu * 16;
    const f32x4 zero4 = {0.f, 0.f, 0.f, 0.f};

    // ---- layer 1: z[16x128] = h[16x32] @ W1[32x128] + b1, relu ----
    bf16x8 a1 = *reinterpret_cast<const bf16x8*>(&lds_h[Mrow0 + l15][l4 * 8]);
#pragma unroll
    for (int n = 0; n < 8; ++n) {
        bf16x8 bfrag = W1F[(n << 6) | lane];          // coalesced 1KB/wave, L2-hot
        f32x4 acc = __builtin_amdgcn_mfma_f32_16x16x32_bf16(a1, bfrag, zero4, 0, 0, 0);
        float b1v = b1[n * 16 + l15];
#pragma unroll
        for (int r = 0; r < 4; ++r)
            lds_z[wu][l4 * 4 + r][n * 16 + l15] = (__bf16)relu_f(acc[r] + b1v);
    }
    // per-wave private z: same-wave write->read, compiler inserts lgkmcnt wait

    // ---- layer 2: o[16x32] = z[16x128] @ W2[128x32] + b2 ----
    f32x4 acc2[2] = {zero4, zero4};
#pragma unroll
    for (int ks = 0; ks < 4; ++ks) {
        bf16x8 a2 = *reinterpret_cast<const bf16x8*>(&lds_z[wu][l15][ks * 32 + l4 * 8]);
#pragma unroll
        for (int nn = 0; nn < 2; ++nn) {
            bf16x8 bfrag = W2F[((ks * 2 + nn) << 6) | lane];
            acc2[nn] = __builtin_amdgcn_mfma_f32_16x16x32_bf16(a2, bfrag, acc2[nn], 0, 0, 0);
        }
    }

    // ---- store: lane holds o[l4*4 + r][nn*16 + l15] ----
#pragma unroll
    for (int nn = 0; nn < 2; ++nn) {
        float b2v = b2[nn * 16 + l15];
#pragma unroll
        for (int r = 0; r < 4; ++r) {
            int row = blockIdx.x * 64 + Mrow0 + l4 * 4 + r;
            if (row < Btot)
                out[row * 32 + nn * 16 + l15] = acc2[nn][r] + b2v;
        }
    }
}

extern "C" void kernel_launch(void* const* d_in, const int* in_sizes, int n_in,
                              void* d_out, int out_size, void* d_ws, size_t ws_size,
                              hipStream_t stream) {
    const float* agent_pos = (const float*)d_in[0];
    const float* agent_vel = (const float*)d_in[1];
    const float* rel_lm    = (const float*)d_in[2];
    const float* other_pos = (const float*)d_in[3];
    const float* lm_pos    = (const float*)d_in[4];
    const float* Wl   = (const float*)d_in[5];
    const float* bl   = (const float*)d_in[6];
    const float* Wr   = (const float*)d_in[7];
    const float* br   = (const float*)d_in[8];
    const float* We   = (const float*)d_in[9];
    const float* att  = (const float*)d_in[10];
    const float* bias = (const float*)d_in[11];
    const float* W1   = (const float*)d_in[12];
    const float* b1   = (const float*)d_in[13];
    const float* W2   = (const float*)d_in[14];
    const float* b2   = (const float*)d_in[15];
    float* out = (float*)d_out;

    __bf16* W1F = (__bf16*)d_ws;                    // 4096 bf16 = 8 KB
    __bf16* W2F = (__bf16*)((char*)d_ws + 8192);    // 4096 bf16 = 8 KB

    prep_weights<<<32, 256, 0, stream>>>(W1, W2, W1F, W2F);

    int B = in_sizes[0] / 6;                  // agent_pos is [B,3,2]
    int samplesPerBlock = 64;
    int grid = (B + samplesPerBlock - 1) / samplesPerBlock;
    scl_fused_kernel<<<grid, 256, 0, stream>>>(
        agent_pos, agent_vel, rel_lm, other_pos, lm_pos,
        Wl, bl, Wr, br, We, att, bias, b1, b2,
        (const bf16x8*)W1F, (const bf16x8*)W2F, out, B);
}